// Round 5
// baseline (3607.684 us; speedup 1.0000x reference)
//
#include <hip/hip_runtime.h>
#include <hip/hip_fp16.h>
#include <stdint.h>

#define NDIST 65536
#define NSTEPS 250

#if __has_builtin(__builtin_rotateleft32)
#define ROTL(x, r) __builtin_rotateleft32((x), (r))
#else
#define ROTL(x, r) (((x) << (r)) | ((x) >> (32 - (r))))
#endif

// Threefry-2x32, 20 rounds, exactly as jax/_src/prng.py. ROTL -> v_alignbit.
#define TF_ROUND(r) { x0 += x1; x1 = ROTL(x1, r); x1 ^= x0; }

__device__ __forceinline__ uint2 threefry2x32(uint32_t ks0, uint32_t ks1, uint32_t ks2,
                                              uint32_t x0, uint32_t x1) {
  x0 += ks0; x1 += ks1;
  TF_ROUND(13) TF_ROUND(15) TF_ROUND(26) TF_ROUND(6)
  x0 += ks1; x1 += ks2 + 1u;
  TF_ROUND(17) TF_ROUND(29) TF_ROUND(16) TF_ROUND(24)
  x0 += ks2; x1 += ks0 + 2u;
  TF_ROUND(13) TF_ROUND(15) TF_ROUND(26) TF_ROUND(6)
  x0 += ks0; x1 += ks1 + 3u;
  TF_ROUND(17) TF_ROUND(29) TF_ROUND(16) TF_ROUND(24)
  x0 += ks1; x1 += ks2 + 4u;
  TF_ROUND(13) TF_ROUND(15) TF_ROUND(26) TF_ROUND(6)
  x0 += ks2; x1 += ks0 + 5u;
  return make_uint2(x0, x1);
}

// R14 stream bisection ledger:
//   partitionable keys + idx = r.y & 0xFFFF        -> absmax 7.59375 (v2,v3,R9)
//   original (non-partitionable) full pipeline     -> absmax 7.6875  (v4)
// => harness JAX is modern (partitionable=True); the bug was the 32-bit
// extraction. jax/_src/prng.py _threefry_random_bits_partitionable for
// bit_width in [8,16,32] returns (bits1 ^ bits2) -- XOR of BOTH output
// words -- not bits2. Chain (re-verified):
//   keys[s] = TF((0,42),(0,s))           (foldlike split, both words)
//   k2      = TF(keys[s],(0,1))          (randint inner split; k1 dead,
//                                         multiplier = 2^32 % 65536 = 0)
//   idx[p]  = (TF(k2,(0,p)).x ^ TF(k2,(0,p)).y) & 0xFFFF

#define WGL 1024
#define GL  16   // 16384 elems per WG -> 512 WGs

__global__ __launch_bounds__(WGL, 1) void fwd_diff_v5(
    const float* __restrict__ x_init,   // [8,1024,1024] fp32
    const float* __restrict__ dist,     // [8,65536] fp32
    float* __restrict__ out) {          // [8,1024,1024] fp32
  extern __shared__ char smem[];
  __half*   tab  = reinterpret_cast<__half*>(smem);            // 128 KB, Bc pre-folded fp16
  uint32_t* keys = reinterpret_cast<uint32_t*>(smem + 131072); // 2 KB step keys (k2 pairs)

  const int tid   = threadIdx.x;
  const int batch = blockIdx.x >> 6;    // 64 WGs per batch
  const int chunk = blockIdx.x & 63;
  const uint32_t base = ((uint32_t)batch << 20) + ((uint32_t)chunk << 14);

  const float Ac = 0.9899494936611665f;  // float32(sqrt(0.98))
  const float Bc = 0.1414213562373095f;  // float32(sqrt(0.02))

  // Stage Bc-folded fp16 table into LDS (vectorized: float4 in, ushort4 out).
  const float4* src = reinterpret_cast<const float4*>(dist + (size_t)batch * NDIST);
  for (int i = tid; i < NDIST / 4; i += WGL) {
    float4 v = src[i];
    ushort4 h;
    h.x = __half_as_ushort(__float2half(Bc * v.x));
    h.y = __half_as_ushort(__float2half(Bc * v.y));
    h.z = __half_as_ushort(__float2half(Bc * v.z));
    h.w = __half_as_ushort(__float2half(Bc * v.w));
    reinterpret_cast<ushort4*>(tab)[i] = h;
  }
  // Step keys (partitionable foldlike): k2 = TF(TF((0,42),(0,s)),(0,1)).
  if (tid < NSTEPS) {
    uint2 ks = threefry2x32(0u, 42u, 0x1BD11BDAu ^ 42u, 0u, (uint32_t)tid);
    uint2 k2 = threefry2x32(ks.x, ks.y, ks.x ^ ks.y ^ 0x1BD11BDAu, 0u, 1u);
    keys[2 * tid]     = k2.x;
    keys[2 * tid + 1] = k2.y;
  }
  __syncthreads();

  uint32_t p[GL];
  float acc[GL];
#pragma unroll
  for (int j = 0; j < GL; ++j) {
    p[j]   = base + (uint32_t)(j * WGL) + (uint32_t)tid;
    acc[j] = x_init[p[j]];
  }

  for (int s = 0; s < NSTEPS; ++s) {
    uint32_t kx = keys[2 * s];
    uint32_t ky = keys[2 * s + 1];
    kx = (uint32_t)__builtin_amdgcn_readfirstlane((int)kx);  // -> SGPR: key adds fold scalar
    ky = (uint32_t)__builtin_amdgcn_readfirstlane((int)ky);
    const uint32_t kz = kx ^ ky ^ 0x1BD11BDAu;

    uint32_t idx[GL];
#pragma unroll
    for (int j = 0; j < GL; ++j) {
      uint2 r = threefry2x32(kx, ky, kz, 0u, p[j]);
      idx[j] = (r.x ^ r.y) & 0xFFFFu;   // partitionable 32-bit draw = bits1^bits2
    }
    // Batch the 16 ds_read_u16 issues, then consume (single lgkm wait window).
#pragma unroll
    for (int j = 0; j < GL; ++j) {
      acc[j] = fmaf(Ac, acc[j], __half2float(tab[idx[j]]));  // Bc folded in table
    }
  }

#pragma unroll
  for (int j = 0; j < GL; ++j) out[p[j]] = acc[j];
}

extern "C" void kernel_launch(void* const* d_in, const int* in_sizes, int n_in,
                              void* d_out, int out_size, void* d_ws, size_t ws_size,
                              hipStream_t stream) {
  const float* x_init = (const float*)d_in[0];
  const float* dist   = (const float*)d_in[1];
  if (n_in >= 2 && in_sizes[0] == 8 * NDIST) {  // defensive swap check
    x_init = (const float*)d_in[1];
    dist   = (const float*)d_in[0];
  }
  float* out = (float*)d_out;
  (void)d_ws; (void)ws_size;

  const int smem = 131072 + 2048;  // 128 KB table + 2 KB keys
  (void)hipFuncSetAttribute(reinterpret_cast<const void*>(fwd_diff_v5),
                            hipFuncAttributeMaxDynamicSharedMemorySize, smem);
  // 8 batches x 64 chunks; 16384 elems/WG (1024 thr x G=16).
  fwd_diff_v5<<<dim3(512), dim3(WGL), smem, stream>>>(x_init, dist, out);
}